// Round 4
// baseline (440.424 us; speedup 1.0000x reference)
//
#include <hip/hip_runtime.h>
#include <hip/hip_bf16.h>

#define N_NODES 100000
#define DEG 16
#define NT16 6250             // 16-row tiles (100000/16)
#define NG64 1563             // 64-row groups (ceil)
#define NB32 3125             // 32-row groups (exact)
#define G1_BLOCKS 782         // 3128 waves -> exactly <=2 tiles/wave
#define G1_WSTRIDE (G1_BLOCKS * 4)
#define FGRID 1024            // persistent grid: 4 blocks/CU x 256 CU, all co-resident

typedef __attribute__((ext_vector_type(8))) short short8;   // 8 bf16
typedef __attribute__((ext_vector_type(4))) float f32x4;
// raw ext-vector types for __builtin_nontemporal_* (HIP struct vectors not accepted)
typedef __attribute__((ext_vector_type(4))) float f4raw;
typedef __attribute__((ext_vector_type(4))) int   i4raw;
typedef __attribute__((ext_vector_type(4))) unsigned u4raw;

__device__ inline unsigned short f2bf(float f) {
    union { float f; unsigned u; } v; v.f = f;
    unsigned u = v.u;
    u += 0x7FFFu + ((u >> 16) & 1u);    // RNE
    return (unsigned short)(u >> 16);
}
__device__ inline unsigned pk2bf(float a, float b) {        // HW v_cvt_pk_bf16_f32 (RNE)
    union { __hip_bfloat162 b2; unsigned u; } v;
    v.b2 = __float22bfloat162_rn(make_float2(a, b));
    return v.u;
}
__device__ inline float bflo(unsigned u) {
    union { unsigned u; float f; } v; v.u = u << 16; return v.f;
}
__device__ inline float bfhi(unsigned u) {
    union { unsigned u; float f; } v; v.u = u & 0xFFFF0000u; return v.f;
}

// ---------------------------------------------------------------------------
// GEMM1: h[M,64](bf16) = X[M,256](fp32) @ W1[256,64](fp32).
// Half-tile software pipeline (spill-free, verified R6/R7); 2 tiles/wave.
// X loads are NON-TEMPORAL: X is stream-once; keep L2 free for the h writes
// so the SpMM phase finds h resident. LDS = 41 KB -> 3 blocks/CU.
// Also zeroes the software-barrier counter for spmm_fused (stream-ordered:
// gemm1 completes, L2 written back at kernel end, before spmm_fused starts).
// ---------------------------------------------------------------------------
__global__ __launch_bounds__(256) void gemm1_k256(const float* __restrict__ X,
                                                  const float* __restrict__ W1,
                                                  unsigned short* __restrict__ h,
                                                  unsigned* __restrict__ barrier_ctr)
{
    __shared__ unsigned short wfrag[256 * 64];      // 32 KB, B-fragment order
    __shared__ unsigned short estage[4][16 * 72];   //  9 KB, per-wave epilogue

    const int tid  = threadIdx.x;
    const int lane = tid & 63;
    const int wid  = tid >> 6;
    const int q    = lane >> 4;
    const int l16  = lane & 15;

    if (blockIdx.x == 0 && tid == 0) *barrier_ctr = 0;   // ws is poisoned; re-init every launch

    // ---- W1 staging: rows kg*4..+3, cols cq*16..+15 per thread ----
    {
        const int kg = tid >> 2;          // 0..63
        const int cq = tid & 3;           // col quarter
        float4 wr[16];
        #pragma unroll
        for (int r = 0; r < 4; ++r)
            #pragma unroll
            for (int i = 0; i < 4; ++i)
                wr[r * 4 + i] = *(const float4*)(W1 + (kg * 4 + r) * 64 + cq * 16 + i * 4);
        const int kb  = kg >> 3;
        const int lnr = (((kg * 4) >> 3) & 3) * 16;
        const int jb  = (kg * 4) & 7;
        #pragma unroll
        for (int c = 0; c < 16; ++c) {
            ushort4 w4;
            #pragma unroll
            for (int r = 0; r < 4; ++r) {
                float4 v = wr[r * 4 + (c >> 2)];
                float  f = ((c & 3) == 0) ? v.x : ((c & 3) == 1) ? v.y :
                           ((c & 3) == 2) ? v.z : v.w;
                ((unsigned short*)&w4)[r] = f2bf(f);
            }
            *(ushort4*)&wfrag[(((kb * 4) + cq) * 64 + lnr + c) * 8 + jb] = w4;
        }
    }
    __syncthreads();

    const int bpidx = (((l16 << 2) | q) << 2);   // source lane * 4 for bpermute
    const size_t xoff = (size_t)(lane >> 2) * 256 + (lane & 3) * 8;

    int t = blockIdx.x * 4 + wid;

    f4raw pa[8];                                  // half0: kb = 0..3
    {
        const float* xb = X + (size_t)t * 16 * 256 + xoff;
        #pragma unroll
        for (int kb = 0; kb < 4; ++kb) {
            pa[2 * kb]     = __builtin_nontemporal_load((const f4raw*)(xb + kb * 32));
            pa[2 * kb + 1] = __builtin_nontemporal_load((const f4raw*)(xb + kb * 32 + 4));
        }
    }

    while (t < NT16) {
        const float* xb = X + (size_t)t * 16 * 256 + xoff;
        f4raw pb[8];                              // half1 loads in flight
        #pragma unroll
        for (int kb = 4; kb < 8; ++kb) {
            pb[2 * (kb - 4)]     = __builtin_nontemporal_load((const f4raw*)(xb + kb * 32));
            pb[2 * (kb - 4) + 1] = __builtin_nontemporal_load((const f4raw*)(xb + kb * 32 + 4));
        }

        f32x4 a0 = {0,0,0,0}, a1 = {0,0,0,0}, a2 = {0,0,0,0}, a3 = {0,0,0,0};

        #pragma unroll
        for (int kb = 0; kb < 4; ++kb) {          // compute half0
            union { int u[4]; short8 s; } uu;
            uu.u[0] = __builtin_amdgcn_ds_bpermute(bpidx, (int)pk2bf(pa[2*kb].x,   pa[2*kb].y));
            uu.u[1] = __builtin_amdgcn_ds_bpermute(bpidx, (int)pk2bf(pa[2*kb].z,   pa[2*kb].w));
            uu.u[2] = __builtin_amdgcn_ds_bpermute(bpidx, (int)pk2bf(pa[2*kb+1].x, pa[2*kb+1].y));
            uu.u[3] = __builtin_amdgcn_ds_bpermute(bpidx, (int)pk2bf(pa[2*kb+1].z, pa[2*kb+1].w));
            const short8* wp = (const short8*)&wfrag[(size_t)((kb * 4) * 64 + lane) * 8];
            a0 = __builtin_amdgcn_mfma_f32_16x16x32_bf16(uu.s, wp[0 * 64], a0, 0, 0, 0);
            a1 = __builtin_amdgcn_mfma_f32_16x16x32_bf16(uu.s, wp[1 * 64], a1, 0, 0, 0);
            a2 = __builtin_amdgcn_mfma_f32_16x16x32_bf16(uu.s, wp[2 * 64], a2, 0, 0, 0);
            a3 = __builtin_amdgcn_mfma_f32_16x16x32_bf16(uu.s, wp[3 * 64], a3, 0, 0, 0);
        }

        const int tn = t + G1_WSTRIDE;            // next tile's half0 in flight
        if (tn < NT16) {
            const float* xn = X + (size_t)tn * 16 * 256 + xoff;
            #pragma unroll
            for (int kb = 0; kb < 4; ++kb) {
                pa[2 * kb]     = __builtin_nontemporal_load((const f4raw*)(xn + kb * 32));
                pa[2 * kb + 1] = __builtin_nontemporal_load((const f4raw*)(xn + kb * 32 + 4));
            }
        }

        #pragma unroll
        for (int kb = 4; kb < 8; ++kb) {          // compute half1
            const int i = kb - 4;
            union { int u[4]; short8 s; } uu;
            uu.u[0] = __builtin_amdgcn_ds_bpermute(bpidx, (int)pk2bf(pb[2*i].x,   pb[2*i].y));
            uu.u[1] = __builtin_amdgcn_ds_bpermute(bpidx, (int)pk2bf(pb[2*i].z,   pb[2*i].w));
            uu.u[2] = __builtin_amdgcn_ds_bpermute(bpidx, (int)pk2bf(pb[2*i+1].x, pb[2*i+1].y));
            uu.u[3] = __builtin_amdgcn_ds_bpermute(bpidx, (int)pk2bf(pb[2*i+1].z, pb[2*i+1].w));
            const short8* wp = (const short8*)&wfrag[(size_t)((kb * 4) * 64 + lane) * 8];
            a0 = __builtin_amdgcn_mfma_f32_16x16x32_bf16(uu.s, wp[0 * 64], a0, 0, 0, 0);
            a1 = __builtin_amdgcn_mfma_f32_16x16x32_bf16(uu.s, wp[1 * 64], a1, 0, 0, 0);
            a2 = __builtin_amdgcn_mfma_f32_16x16x32_bf16(uu.s, wp[2 * 64], a2, 0, 0, 0);
            a3 = __builtin_amdgcn_mfma_f32_16x16x32_bf16(uu.s, wp[3 * 64], a3, 0, 0, 0);
        }

        // epilogue: D[q*4+r][ct*16+l16] -> bf16 rows via per-wave LDS
        unsigned short* st = estage[wid];
        #pragma unroll
        for (int r = 0; r < 4; ++r) {
            int rr = (q * 4 + r) * 72 + l16;
            st[rr + 0 * 16] = f2bf(a0[r]);
            st[rr + 1 * 16] = f2bf(a1[r]);
            st[rr + 2 * 16] = f2bf(a2[r]);
            st[rr + 3 * 16] = f2bf(a3[r]);
        }
        #pragma unroll
        for (int i = 0; i < 4; ++i) {
            int row = i * 4 + q;
            uint2 v = *(const uint2*)&st[row * 72 + l16 * 4];
            *(uint2*)(h + (size_t)(t * 16 + row) * 64 + l16 * 4) = v;   // cached: SpMM reuses
        }
        t = tn;
    }
}

// ---------------------------------------------------------------------------
// Row gather, 8 lanes/row x uint4; colind/vals loads NON-TEMPORAL (stream-once)
// so they don't evict gather lines from L2.
// ---------------------------------------------------------------------------
__device__ inline void gather_row8(const unsigned short* __restrict__ B,
                                   const int* __restrict__ ci,
                                   const float* __restrict__ vv,
                                   int j8, float* __restrict__ acc)
{
    #pragma unroll
    for (int b = 0; b < 2; ++b) {
        i4raw c0 = __builtin_nontemporal_load((const i4raw*)ci + 2 * b);
        i4raw c1 = __builtin_nontemporal_load((const i4raw*)ci + 2 * b + 1);
        f4raw v0 = __builtin_nontemporal_load((const f4raw*)vv + 2 * b);
        f4raw v1 = __builtin_nontemporal_load((const f4raw*)vv + 2 * b + 1);
        uint4 g0 = *(const uint4*)(B + (size_t)c0.x * 64 + j8 * 8);
        uint4 g1 = *(const uint4*)(B + (size_t)c0.y * 64 + j8 * 8);
        uint4 g2 = *(const uint4*)(B + (size_t)c0.z * 64 + j8 * 8);
        uint4 g3 = *(const uint4*)(B + (size_t)c0.w * 64 + j8 * 8);
        uint4 g4 = *(const uint4*)(B + (size_t)c1.x * 64 + j8 * 8);
        uint4 g5 = *(const uint4*)(B + (size_t)c1.y * 64 + j8 * 8);
        uint4 g6 = *(const uint4*)(B + (size_t)c1.z * 64 + j8 * 8);
        uint4 g7 = *(const uint4*)(B + (size_t)c1.w * 64 + j8 * 8);
#define ACC8(g, s) \
        acc[0] += (s) * bflo((g).x); acc[1] += (s) * bfhi((g).x); \
        acc[2] += (s) * bflo((g).y); acc[3] += (s) * bfhi((g).y); \
        acc[4] += (s) * bflo((g).z); acc[5] += (s) * bfhi((g).z); \
        acc[6] += (s) * bflo((g).w); acc[7] += (s) * bfhi((g).w);
        ACC8(g0, v0.x) ACC8(g1, v0.y) ACC8(g2, v0.z) ACC8(g3, v0.w)
        ACC8(g4, v1.x) ACC8(g5, v1.y) ACC8(g6, v1.z) ACC8(g7, v1.w)
#undef ACC8
    }
}

// ---------------------------------------------------------------------------
// Fused persistent SpMM pipeline (plain launch, software grid barrier):
//   phase 1: o1 = bf16( relu(A @ h) @ W2 )    [1563 virtual 64-row blocks]
//   phase 2: out = A @ o1 (fp32)              [3125 virtual 32-row blocks]
// Co-residency arithmetic: __launch_bounds__(256,4) caps VGPR at 128 ->
// 4 waves/SIMD -> 4 blocks/CU; LDS 17 KB <= 40 KB/block; 4 x 256 = 1024
// blocks all resident => software barrier cannot deadlock.
// Barrier coherence: ACQ_REL arrival writes back the XCD L2 (o1 -> L3);
// ACQUIRE spin-exit invalidates it (no stale poison lines for phase 2).
// ---------------------------------------------------------------------------
__global__ __launch_bounds__(256, 4) void spmm_fused(const int* __restrict__ colind,
                                                     const float* __restrict__ vals,
                                                     const unsigned short* __restrict__ h,
                                                     const float* __restrict__ W2,
                                                     unsigned short* __restrict__ o1,
                                                     float* __restrict__ out,
                                                     unsigned* __restrict__ barrier_ctr)
{
    __shared__ unsigned short wfrag2[64 * 64];      // 8 KB
    __shared__ unsigned short stage[4][16 * 72];    // 9 KB

    const int tid  = threadIdx.x;
    const int lane = tid & 63;
    const int wid  = tid >> 6;
    const int q    = lane >> 4;
    const int l16  = lane & 15;
    const int rl   = lane >> 3;
    const int j8   = lane & 7;

    // ---- W2 staging (once per block) ----
    {
        const int r4 = tid >> 2;
        const int qt = tid & 3;
        float4 wr[4];
        #pragma unroll
        for (int i = 0; i < 4; ++i)
            wr[i] = *(const float4*)(W2 + r4 * 64 + qt * 16 + i * 4);
        const int kb  = r4 >> 5;
        const int j   = r4 & 7;
        const int lnr = ((r4 >> 3) & 3) * 16;
        #pragma unroll
        for (int c = 0; c < 16; ++c) {
            float f = ((c & 3) == 0) ? wr[c >> 2].x :
                      ((c & 3) == 1) ? wr[c >> 2].y :
                      ((c & 3) == 2) ? wr[c >> 2].z : wr[c >> 2].w;
            wfrag2[(((kb * 4) + qt) * 64 + lnr + c) * 8 + j] = f2bf(f);
        }
    }
    __syncthreads();

    unsigned short* st = stage[wid];

    // ---------------- phase 1: o1 = bf16(relu(A@h) @ W2) ----------------
    for (int vb = blockIdx.x; vb < NG64; vb += FGRID) {
        const int base = vb * 64 + wid * 16;

        #pragma unroll
        for (int p = 0; p < 2; ++p) {
            int lr  = p * 8 + rl;
            int row = base + lr;
            int rc  = row < N_NODES ? row : N_NODES - 1;
            float acc[8] = {0.f,0.f,0.f,0.f,0.f,0.f,0.f,0.f};
            gather_row8(h, colind + (size_t)rc * DEG, vals + (size_t)rc * DEG, j8, acc);
            uint4 pk;
            pk.x = pk2bf(fmaxf(acc[0], 0.f), fmaxf(acc[1], 0.f));
            pk.y = pk2bf(fmaxf(acc[2], 0.f), fmaxf(acc[3], 0.f));
            pk.z = pk2bf(fmaxf(acc[4], 0.f), fmaxf(acc[5], 0.f));
            pk.w = pk2bf(fmaxf(acc[6], 0.f), fmaxf(acc[7], 0.f));
            *(uint4*)&st[lr * 72 + j8 * 8] = pk;
        }
        // wave-private LDS slice: DS ops in-order per wave, no barrier needed

        f32x4 a0 = {0,0,0,0}, a1 = {0,0,0,0}, a2 = {0,0,0,0}, a3 = {0,0,0,0};
        #pragma unroll
        for (int kb = 0; kb < 2; ++kb) {
            short8 af = *(const short8*)&st[l16 * 72 + kb * 32 + q * 8];
            const short8* wp = (const short8*)&wfrag2[(size_t)((kb * 4) * 64 + lane) * 8];
            a0 = __builtin_amdgcn_mfma_f32_16x16x32_bf16(af, wp[0 * 64], a0, 0, 0, 0);
            a1 = __builtin_amdgcn_mfma_f32_16x16x32_bf16(af, wp[1 * 64], a1, 0, 0, 0);
            a2 = __builtin_amdgcn_mfma_f32_16x16x32_bf16(af, wp[2 * 64], a2, 0, 0, 0);
            a3 = __builtin_amdgcn_mfma_f32_16x16x32_bf16(af, wp[3 * 64], a3, 0, 0, 0);
        }
        #pragma unroll
        for (int r = 0; r < 4; ++r) {
            int rr = (q * 4 + r) * 72 + l16;
            st[rr + 0 * 16] = f2bf(a0[r]);
            st[rr + 1 * 16] = f2bf(a1[r]);
            st[rr + 2 * 16] = f2bf(a2[r]);
            st[rr + 3 * 16] = f2bf(a3[r]);
        }
        #pragma unroll
        for (int i = 0; i < 4; ++i) {
            int row = base + i * 4 + q;
            if (row < N_NODES) {
                uint2 v = *(const uint2*)&st[(i * 4 + q) * 72 + l16 * 4];
                *(uint2*)(o1 + (size_t)row * 64 + l16 * 4) = v;
            }
        }
    }

    // ---------------- software grid barrier ----------------
    __syncthreads();                       // all waves' o1 stores drained (vmcnt) & retired
    if (tid == 0) {
        // release: writes back this XCD's dirty L2 lines (o1) before arrival
        __hip_atomic_fetch_add(barrier_ctr, 1u, __ATOMIC_ACQ_REL, __HIP_MEMORY_SCOPE_AGENT);
        // acquire: spin until all 1024 blocks arrived; exit invalidates L2
        while (__hip_atomic_load(barrier_ctr, __ATOMIC_ACQUIRE, __HIP_MEMORY_SCOPE_AGENT) < FGRID) {
            __builtin_amdgcn_s_sleep(32);
        }
    }
    __syncthreads();
    __threadfence();                       // belt-and-braces acquire for all threads

    // ---------------- phase 2: out = A @ o1 (fp32) ----------------
    for (int vb = blockIdx.x; vb < NB32; vb += FGRID) {
        const int row = vb * 32 + wid * 8 + rl;    // 3125*32 = 100000 exact
        float acc[8] = {0.f,0.f,0.f,0.f,0.f,0.f,0.f,0.f};
        gather_row8(o1, colind + (size_t)row * DEG, vals + (size_t)row * DEG, j8, acc);

        f4raw lo = { acc[0], acc[1], acc[2], acc[3] };
        f4raw hi = { acc[4], acc[5], acc[6], acc[7] };
        float* op = out + (size_t)row * 64 + j8 * 8;
        *(f4raw*)op       = lo;    // cached: full-line merge in L2 (R3 finding)
        *(f4raw*)(op + 4) = hi;
    }
}

extern "C" void kernel_launch(void* const* d_in, const int* in_sizes, int n_in,
                              void* d_out, int out_size, void* d_ws, size_t ws_size,
                              hipStream_t stream) {
    const float* X      = (const float*)d_in[0];   // [N,256]
    const float* W1     = (const float*)d_in[1];   // [256,64]
    const float* W2     = (const float*)d_in[2];   // [64,64]
    const float* vals   = (const float*)d_in[3];   // [NNZ]
    // d_in[4] = rowptr (fixed degree, unused)
    const int*   colind = (const int*)d_in[5];     // [NNZ]
    float*       out    = (float*)d_out;           // [N,64] fp32

    unsigned short* h  = (unsigned short*)d_ws;        // [N,64] bf16
    unsigned short* o1 = h + (size_t)N_NODES * 64;     // [N,64] bf16 (no alias)
    unsigned* barrier_ctr = (unsigned*)(o1 + (size_t)N_NODES * 64);  // 4B past o1

    hipLaunchKernelGGL(gemm1_k256, dim3(G1_BLOCKS), dim3(256), 0, stream, X, W1, h, barrier_ctr);
    hipLaunchKernelGGL(spmm_fused, dim3(FGRID), dim3(256), 0, stream,
                       colind, vals, h, W2, o1, out, barrier_ctr);
}

// Round 5
// 230.388 us; speedup vs baseline: 1.9117x; 1.9117x over previous
//
#include <hip/hip_runtime.h>
#include <hip/hip_bf16.h>

#define N_NODES 100000
#define DEG 16
#define NT16 6250             // 16-row tiles (100000/16)
#define NG64 1563             // 64-row groups (ceil)
#define G1_BLOCKS 782         // 3128 wave-slots -> exactly <=2 tiles/wave
#define G1_WSTRIDE (G1_BLOCKS * 4)

typedef __attribute__((ext_vector_type(8))) short short8;   // 8 bf16
typedef __attribute__((ext_vector_type(4))) float f32x4;
// raw ext-vector types for __builtin_nontemporal_* (HIP struct vectors not accepted)
typedef __attribute__((ext_vector_type(4))) float f4raw;
typedef __attribute__((ext_vector_type(4))) int   i4raw;
typedef __attribute__((ext_vector_type(4))) unsigned u4raw;

__device__ inline unsigned short f2bf(float f) {
    union { float f; unsigned u; } v; v.f = f;
    unsigned u = v.u;
    u += 0x7FFFu + ((u >> 16) & 1u);    // RNE
    return (unsigned short)(u >> 16);
}
__device__ inline unsigned pk2bf(float a, float b) {        // HW v_cvt_pk_bf16_f32 (RNE)
    union { __hip_bfloat162 b2; unsigned u; } v;
    v.b2 = __float22bfloat162_rn(make_float2(a, b));
    return v.u;
}
__device__ inline float bflo(unsigned u) {
    union { unsigned u; float f; } v; v.u = u << 16; return v.f;
}
__device__ inline float bfhi(unsigned u) {
    union { unsigned u; float f; } v; v.u = u & 0xFFFF0000u; return v.f;
}

// ---------------------------------------------------------------------------
// GEMM1: h[M,64](bf16) = X[M,256](fp32) @ W1[256,64](fp32).
// Half-tile software pipeline (spill-free); 2 tiles/wave.
// X loads NON-TEMPORAL: keep L2 free for h writes (spmm_gemm2 reuses h).
// R5: epilogue LDS (estage, 9 KB) removed — accumulators stored DIRECTLY to
// h via the C/D layout (row=q*4+r, col=ct*16+l16). LDS 41 KB -> 32 KB ->
// 5 blocks/CU (12 -> 20 waves/CU). R4 showed the miss path is concurrency-
// bound: +67% waves -> proportional gemm1 speedup expected.
// ---------------------------------------------------------------------------
__global__ __launch_bounds__(256) void gemm1_k256(const float* __restrict__ X,
                                                  const float* __restrict__ W1,
                                                  unsigned short* __restrict__ h)
{
    __shared__ unsigned short wfrag[256 * 64];      // 32 KB, B-fragment order

    const int tid  = threadIdx.x;
    const int lane = tid & 63;
    const int wid  = tid >> 6;
    const int q    = lane >> 4;
    const int l16  = lane & 15;

    // ---- W1 staging: rows kg*4..+3, cols cq*16..+15 per thread ----
    {
        const int kg = tid >> 2;          // 0..63
        const int cq = tid & 3;           // col quarter
        float4 wr[16];
        #pragma unroll
        for (int r = 0; r < 4; ++r)
            #pragma unroll
            for (int i = 0; i < 4; ++i)
                wr[r * 4 + i] = *(const float4*)(W1 + (kg * 4 + r) * 64 + cq * 16 + i * 4);
        const int kb  = kg >> 3;
        const int lnr = (((kg * 4) >> 3) & 3) * 16;
        const int jb  = (kg * 4) & 7;
        #pragma unroll
        for (int c = 0; c < 16; ++c) {
            ushort4 w4;
            #pragma unroll
            for (int r = 0; r < 4; ++r) {
                float4 v = wr[r * 4 + (c >> 2)];
                float  f = ((c & 3) == 0) ? v.x : ((c & 3) == 1) ? v.y :
                           ((c & 3) == 2) ? v.z : v.w;
                ((unsigned short*)&w4)[r] = f2bf(f);
            }
            *(ushort4*)&wfrag[(((kb * 4) + cq) * 64 + lnr + c) * 8 + jb] = w4;
        }
    }
    __syncthreads();

    const int bpidx = (((l16 << 2) | q) << 2);   // source lane * 4 for bpermute
    const size_t xoff = (size_t)(lane >> 2) * 256 + (lane & 3) * 8;

    int t = blockIdx.x * 4 + wid;

    f4raw pa[8];                                  // half0: kb = 0..3
    {
        const float* xb = X + (size_t)t * 16 * 256 + xoff;
        #pragma unroll
        for (int kb = 0; kb < 4; ++kb) {
            pa[2 * kb]     = __builtin_nontemporal_load((const f4raw*)(xb + kb * 32));
            pa[2 * kb + 1] = __builtin_nontemporal_load((const f4raw*)(xb + kb * 32 + 4));
        }
    }

    while (t < NT16) {
        const float* xb = X + (size_t)t * 16 * 256 + xoff;
        f4raw pb[8];                              // half1 loads in flight
        #pragma unroll
        for (int kb = 4; kb < 8; ++kb) {
            pb[2 * (kb - 4)]     = __builtin_nontemporal_load((const f4raw*)(xb + kb * 32));
            pb[2 * (kb - 4) + 1] = __builtin_nontemporal_load((const f4raw*)(xb + kb * 32 + 4));
        }

        f32x4 a0 = {0,0,0,0}, a1 = {0,0,0,0}, a2 = {0,0,0,0}, a3 = {0,0,0,0};

        #pragma unroll
        for (int kb = 0; kb < 4; ++kb) {          // compute half0
            union { int u[4]; short8 s; } uu;
            uu.u[0] = __builtin_amdgcn_ds_bpermute(bpidx, (int)pk2bf(pa[2*kb].x,   pa[2*kb].y));
            uu.u[1] = __builtin_amdgcn_ds_bpermute(bpidx, (int)pk2bf(pa[2*kb].z,   pa[2*kb].w));
            uu.u[2] = __builtin_amdgcn_ds_bpermute(bpidx, (int)pk2bf(pa[2*kb+1].x, pa[2*kb+1].y));
            uu.u[3] = __builtin_amdgcn_ds_bpermute(bpidx, (int)pk2bf(pa[2*kb+1].z, pa[2*kb+1].w));
            const short8* wp = (const short8*)&wfrag[(size_t)((kb * 4) * 64 + lane) * 8];
            a0 = __builtin_amdgcn_mfma_f32_16x16x32_bf16(uu.s, wp[0 * 64], a0, 0, 0, 0);
            a1 = __builtin_amdgcn_mfma_f32_16x16x32_bf16(uu.s, wp[1 * 64], a1, 0, 0, 0);
            a2 = __builtin_amdgcn_mfma_f32_16x16x32_bf16(uu.s, wp[2 * 64], a2, 0, 0, 0);
            a3 = __builtin_amdgcn_mfma_f32_16x16x32_bf16(uu.s, wp[3 * 64], a3, 0, 0, 0);
        }

        const int tn = t + G1_WSTRIDE;            // next tile's half0 in flight
        if (tn < NT16) {
            const float* xn = X + (size_t)tn * 16 * 256 + xoff;
            #pragma unroll
            for (int kb = 0; kb < 4; ++kb) {
                pa[2 * kb]     = __builtin_nontemporal_load((const f4raw*)(xn + kb * 32));
                pa[2 * kb + 1] = __builtin_nontemporal_load((const f4raw*)(xn + kb * 32 + 4));
            }
        }

        #pragma unroll
        for (int kb = 4; kb < 8; ++kb) {          // compute half1
            const int i = kb - 4;
            union { int u[4]; short8 s; } uu;
            uu.u[0] = __builtin_amdgcn_ds_bpermute(bpidx, (int)pk2bf(pb[2*i].x,   pb[2*i].y));
            uu.u[1] = __builtin_amdgcn_ds_bpermute(bpidx, (int)pk2bf(pb[2*i].z,   pb[2*i].w));
            uu.u[2] = __builtin_amdgcn_ds_bpermute(bpidx, (int)pk2bf(pb[2*i+1].x, pb[2*i+1].y));
            uu.u[3] = __builtin_amdgcn_ds_bpermute(bpidx, (int)pk2bf(pb[2*i+1].z, pb[2*i+1].w));
            const short8* wp = (const short8*)&wfrag[(size_t)((kb * 4) * 64 + lane) * 8];
            a0 = __builtin_amdgcn_mfma_f32_16x16x32_bf16(uu.s, wp[0 * 64], a0, 0, 0, 0);
            a1 = __builtin_amdgcn_mfma_f32_16x16x32_bf16(uu.s, wp[1 * 64], a1, 0, 0, 0);
            a2 = __builtin_amdgcn_mfma_f32_16x16x32_bf16(uu.s, wp[2 * 64], a2, 0, 0, 0);
            a3 = __builtin_amdgcn_mfma_f32_16x16x32_bf16(uu.s, wp[3 * 64], a3, 0, 0, 0);
        }

        // epilogue: direct store. D[q*4+r][ct*16+l16] = a_ct[r]; per (r,ct)
        // the 16 lanes of a q-group write 32 B contiguous — L2 merges lines.
        {
            unsigned short* hrow = h + (size_t)(t * 16) * 64;
            #pragma unroll
            for (int r = 0; r < 4; ++r) {
                const int row = q * 4 + r;
                hrow[row * 64 +  0 + l16] = f2bf(a0[r]);
                hrow[row * 64 + 16 + l16] = f2bf(a1[r]);
                hrow[row * 64 + 32 + l16] = f2bf(a2[r]);
                hrow[row * 64 + 48 + l16] = f2bf(a3[r]);
            }
        }
        t = tn;
    }
}

// ---------------------------------------------------------------------------
// Row gather, 8 lanes/row x uint4; colind/vals loads NON-TEMPORAL (stream-once)
// so they don't evict gather lines from L2.
// ---------------------------------------------------------------------------
__device__ inline void gather_row8(const unsigned short* __restrict__ B,
                                   const int* __restrict__ ci,
                                   const float* __restrict__ vv,
                                   int j8, float* __restrict__ acc)
{
    #pragma unroll
    for (int b = 0; b < 2; ++b) {
        i4raw c0 = __builtin_nontemporal_load((const i4raw*)ci + 2 * b);
        i4raw c1 = __builtin_nontemporal_load((const i4raw*)ci + 2 * b + 1);
        f4raw v0 = __builtin_nontemporal_load((const f4raw*)vv + 2 * b);
        f4raw v1 = __builtin_nontemporal_load((const f4raw*)vv + 2 * b + 1);
        uint4 g0 = *(const uint4*)(B + (size_t)c0.x * 64 + j8 * 8);
        uint4 g1 = *(const uint4*)(B + (size_t)c0.y * 64 + j8 * 8);
        uint4 g2 = *(const uint4*)(B + (size_t)c0.z * 64 + j8 * 8);
        uint4 g3 = *(const uint4*)(B + (size_t)c0.w * 64 + j8 * 8);
        uint4 g4 = *(const uint4*)(B + (size_t)c1.x * 64 + j8 * 8);
        uint4 g5 = *(const uint4*)(B + (size_t)c1.y * 64 + j8 * 8);
        uint4 g6 = *(const uint4*)(B + (size_t)c1.z * 64 + j8 * 8);
        uint4 g7 = *(const uint4*)(B + (size_t)c1.w * 64 + j8 * 8);
#define ACC8(g, s) \
        acc[0] += (s) * bflo((g).x); acc[1] += (s) * bfhi((g).x); \
        acc[2] += (s) * bflo((g).y); acc[3] += (s) * bfhi((g).y); \
        acc[4] += (s) * bflo((g).z); acc[5] += (s) * bfhi((g).z); \
        acc[6] += (s) * bflo((g).w); acc[7] += (s) * bfhi((g).w);
        ACC8(g0, v0.x) ACC8(g1, v0.y) ACC8(g2, v0.z) ACC8(g3, v0.w)
        ACC8(g4, v1.x) ACC8(g5, v1.y) ACC8(g6, v1.z) ACC8(g7, v1.w)
#undef ACC8
    }
}

// ---------------------------------------------------------------------------
// Fused SpMM1 + ReLU + GEMM2: o1 = bf16( relu(A @ h) @ W2 ).  17 KB LDS.
// (unchanged from verified R3)
// ---------------------------------------------------------------------------
__global__ __launch_bounds__(256) void spmm_gemm2(const int* __restrict__ colind,
                                                  const float* __restrict__ vals,
                                                  const unsigned short* __restrict__ h,
                                                  const float* __restrict__ W2,
                                                  unsigned short* __restrict__ o1)
{
    __shared__ unsigned short wfrag2[64 * 64];      // 8 KB
    __shared__ unsigned short stage[4][16 * 72];    // 9 KB

    const int tid  = threadIdx.x;
    const int lane = tid & 63;
    const int wid  = tid >> 6;
    const int q    = lane >> 4;
    const int l16  = lane & 15;

    // ---- W2 staging ----
    {
        const int r4 = tid >> 2;
        const int qt = tid & 3;
        float4 wr[4];
        #pragma unroll
        for (int i = 0; i < 4; ++i)
            wr[i] = *(const float4*)(W2 + r4 * 64 + qt * 16 + i * 4);
        const int kb  = r4 >> 5;
        const int j   = r4 & 7;
        const int lnr = ((r4 >> 3) & 3) * 16;
        #pragma unroll
        for (int c = 0; c < 16; ++c) {
            float f = ((c & 3) == 0) ? wr[c >> 2].x :
                      ((c & 3) == 1) ? wr[c >> 2].y :
                      ((c & 3) == 2) ? wr[c >> 2].z : wr[c >> 2].w;
            wfrag2[(((kb * 4) + qt) * 64 + lnr + c) * 8 + j] = f2bf(f);
        }
    }
    __syncthreads();

    const int base = blockIdx.x * 64 + wid * 16;    // grid 1563 covers 100032
    unsigned short* st = stage[wid];
    const int rl = lane >> 3;
    const int j8 = lane & 7;

    #pragma unroll
    for (int p = 0; p < 2; ++p) {
        int lr  = p * 8 + rl;
        int row = base + lr;
        int rc  = row < N_NODES ? row : N_NODES - 1;
        float acc[8] = {0.f,0.f,0.f,0.f,0.f,0.f,0.f,0.f};
        gather_row8(h, colind + (size_t)rc * DEG, vals + (size_t)rc * DEG, j8, acc);
        uint4 pk;
        pk.x = pk2bf(fmaxf(acc[0], 0.f), fmaxf(acc[1], 0.f));
        pk.y = pk2bf(fmaxf(acc[2], 0.f), fmaxf(acc[3], 0.f));
        pk.z = pk2bf(fmaxf(acc[4], 0.f), fmaxf(acc[5], 0.f));
        pk.w = pk2bf(fmaxf(acc[6], 0.f), fmaxf(acc[7], 0.f));
        *(uint4*)&st[lr * 72 + j8 * 8] = pk;
    }
    // wave-private LDS slice: DS ops in-order per wave, no barrier needed

    f32x4 a0 = {0,0,0,0}, a1 = {0,0,0,0}, a2 = {0,0,0,0}, a3 = {0,0,0,0};
    #pragma unroll
    for (int kb = 0; kb < 2; ++kb) {
        short8 af = *(const short8*)&st[l16 * 72 + kb * 32 + q * 8];
        const short8* wp = (const short8*)&wfrag2[(size_t)((kb * 4) * 64 + lane) * 8];
        a0 = __builtin_amdgcn_mfma_f32_16x16x32_bf16(af, wp[0 * 64], a0, 0, 0, 0);
        a1 = __builtin_amdgcn_mfma_f32_16x16x32_bf16(af, wp[1 * 64], a1, 0, 0, 0);
        a2 = __builtin_amdgcn_mfma_f32_16x16x32_bf16(af, wp[2 * 64], a2, 0, 0, 0);
        a3 = __builtin_amdgcn_mfma_f32_16x16x32_bf16(af, wp[3 * 64], a3, 0, 0, 0);
    }
    #pragma unroll
    for (int r = 0; r < 4; ++r) {
        int rr = (q * 4 + r) * 72 + l16;
        st[rr + 0 * 16] = f2bf(a0[r]);
        st[rr + 1 * 16] = f2bf(a1[r]);
        st[rr + 2 * 16] = f2bf(a2[r]);
        st[rr + 3 * 16] = f2bf(a3[r]);
    }
    #pragma unroll
    for (int i = 0; i < 4; ++i) {
        int row = base + i * 4 + q;
        if (row < N_NODES) {
            uint2 v = *(const uint2*)&st[(i * 4 + q) * 72 + l16 * 4];
            *(uint2*)(o1 + (size_t)row * 64 + l16 * 4) = v;   // cached: spmm2 reuses
        }
    }
}

// ---------------------------------------------------------------------------
// SpMM2: out(fp32) = A @ o1(bf16). Grid 3125 exact, no LDS.
// Cached float4 stores (R3): full-line merge in L2, WRITE_SIZE ~26 MB.
// ---------------------------------------------------------------------------
__global__ __launch_bounds__(256) void spmm_out(const int* __restrict__ colind,
                                                const float* __restrict__ vals,
                                                const unsigned short* __restrict__ B,
                                                float* __restrict__ out)
{
    const int tid  = threadIdx.x;
    const int lane = tid & 63;
    const int wid  = tid >> 6;
    const int rl   = lane >> 3;
    const int j8   = lane & 7;
    const int row  = blockIdx.x * 32 + wid * 8 + rl;   // 3125*32 = 100000 exact

    float acc[8] = {0.f,0.f,0.f,0.f,0.f,0.f,0.f,0.f};
    gather_row8(B, colind + (size_t)row * DEG, vals + (size_t)row * DEG, j8, acc);

    f4raw lo = { acc[0], acc[1], acc[2], acc[3] };
    f4raw hi = { acc[4], acc[5], acc[6], acc[7] };
    float* op = out + (size_t)row * 64 + j8 * 8;
    *(f4raw*)op       = lo;     // cached: full-line merge in L2
    *(f4raw*)(op + 4) = hi;
}

extern "C" void kernel_launch(void* const* d_in, const int* in_sizes, int n_in,
                              void* d_out, int out_size, void* d_ws, size_t ws_size,
                              hipStream_t stream) {
    const float* X      = (const float*)d_in[0];   // [N,256]
    const float* W1     = (const float*)d_in[1];   // [256,64]
    const float* W2     = (const float*)d_in[2];   // [64,64]
    const float* vals   = (const float*)d_in[3];   // [NNZ]
    // d_in[4] = rowptr (fixed degree, unused)
    const int*   colind = (const int*)d_in[5];     // [NNZ]
    float*       out    = (float*)d_out;           // [N,64] fp32

    unsigned short* h  = (unsigned short*)d_ws;        // [N,64] bf16
    unsigned short* o1 = h + (size_t)N_NODES * 64;     // [N,64] bf16 (no alias)

    hipLaunchKernelGGL(gemm1_k256, dim3(G1_BLOCKS), dim3(256), 0, stream, X, W1, h);
    hipLaunchKernelGGL(spmm_gemm2, dim3(NG64), dim3(256), 0, stream,
                       colind, vals, h, W2, o1);
    hipLaunchKernelGGL(spmm_out, dim3(N_NODES / 32), dim3(256), 0, stream,
                       colind, vals, o1, out);
}

// Round 6
// 228.915 us; speedup vs baseline: 1.9240x; 1.0064x over previous
//
#include <hip/hip_runtime.h>
#include <hip/hip_bf16.h>

#define N_NODES 100000
#define DEG 16
#define NT16 6250             // 16-row tiles (100000/16)
#define NB32 3125             // 32-row blocks (exact: 3125*32 = 100000)
#define G1_BLOCKS 782         // 3128 wave-slots -> exactly <=2 tiles/wave
#define G1_WSTRIDE (G1_BLOCKS * 4)

typedef __attribute__((ext_vector_type(8))) short short8;   // 8 bf16
typedef __attribute__((ext_vector_type(4))) float f32x4;
// raw ext-vector types for __builtin_nontemporal_* (HIP struct vectors not accepted)
typedef __attribute__((ext_vector_type(4))) float f4raw;
typedef __attribute__((ext_vector_type(4))) int   i4raw;
typedef __attribute__((ext_vector_type(4))) unsigned u4raw;

__device__ inline unsigned short f2bf(float f) {
    union { float f; unsigned u; } v; v.f = f;
    unsigned u = v.u;
    u += 0x7FFFu + ((u >> 16) & 1u);    // RNE
    return (unsigned short)(u >> 16);
}
__device__ inline unsigned pk2bf(float a, float b) {        // HW v_cvt_pk_bf16_f32 (RNE)
    union { __hip_bfloat162 b2; unsigned u; } v;
    v.b2 = __float22bfloat162_rn(make_float2(a, b));
    return v.u;
}
__device__ inline float bflo(unsigned u) {
    union { unsigned u; float f; } v; v.u = u << 16; return v.f;
}
__device__ inline float bfhi(unsigned u) {
    union { unsigned u; float f; } v; v.u = u & 0xFFFF0000u; return v.f;
}

// ---------------------------------------------------------------------------
// GEMM1: h[M,64](bf16) = X[M,256](fp32) @ W1[256,64](fp32).
// Half-tile software pipeline (spill-free); 2 tiles/wave. X loads NT.
// R5: direct accumulator->h stores (no epilogue LDS); 32 KB LDS.
// R5 result: neutral => gemm1 is small & BW-bound (~20-25 us). Keep.
// ---------------------------------------------------------------------------
__global__ __launch_bounds__(256) void gemm1_k256(const float* __restrict__ X,
                                                  const float* __restrict__ W1,
                                                  unsigned short* __restrict__ h)
{
    __shared__ unsigned short wfrag[256 * 64];      // 32 KB, B-fragment order

    const int tid  = threadIdx.x;
    const int lane = tid & 63;
    const int wid  = tid >> 6;
    const int q    = lane >> 4;
    const int l16  = lane & 15;

    // ---- W1 staging: rows kg*4..+3, cols cq*16..+15 per thread ----
    {
        const int kg = tid >> 2;          // 0..63
        const int cq = tid & 3;           // col quarter
        float4 wr[16];
        #pragma unroll
        for (int r = 0; r < 4; ++r)
            #pragma unroll
            for (int i = 0; i < 4; ++i)
                wr[r * 4 + i] = *(const float4*)(W1 + (kg * 4 + r) * 64 + cq * 16 + i * 4);
        const int kb  = kg >> 3;
        const int lnr = (((kg * 4) >> 3) & 3) * 16;
        const int jb  = (kg * 4) & 7;
        #pragma unroll
        for (int c = 0; c < 16; ++c) {
            ushort4 w4;
            #pragma unroll
            for (int r = 0; r < 4; ++r) {
                float4 v = wr[r * 4 + (c >> 2)];
                float  f = ((c & 3) == 0) ? v.x : ((c & 3) == 1) ? v.y :
                           ((c & 3) == 2) ? v.z : v.w;
                ((unsigned short*)&w4)[r] = f2bf(f);
            }
            *(ushort4*)&wfrag[(((kb * 4) + cq) * 64 + lnr + c) * 8 + jb] = w4;
        }
    }
    __syncthreads();

    const int bpidx = (((l16 << 2) | q) << 2);   // source lane * 4 for bpermute
    const size_t xoff = (size_t)(lane >> 2) * 256 + (lane & 3) * 8;

    int t = blockIdx.x * 4 + wid;

    f4raw pa[8];                                  // half0: kb = 0..3
    {
        const float* xb = X + (size_t)t * 16 * 256 + xoff;
        #pragma unroll
        for (int kb = 0; kb < 4; ++kb) {
            pa[2 * kb]     = __builtin_nontemporal_load((const f4raw*)(xb + kb * 32));
            pa[2 * kb + 1] = __builtin_nontemporal_load((const f4raw*)(xb + kb * 32 + 4));
        }
    }

    while (t < NT16) {
        const float* xb = X + (size_t)t * 16 * 256 + xoff;
        f4raw pb[8];                              // half1 loads in flight
        #pragma unroll
        for (int kb = 4; kb < 8; ++kb) {
            pb[2 * (kb - 4)]     = __builtin_nontemporal_load((const f4raw*)(xb + kb * 32));
            pb[2 * (kb - 4) + 1] = __builtin_nontemporal_load((const f4raw*)(xb + kb * 32 + 4));
        }

        f32x4 a0 = {0,0,0,0}, a1 = {0,0,0,0}, a2 = {0,0,0,0}, a3 = {0,0,0,0};

        #pragma unroll
        for (int kb = 0; kb < 4; ++kb) {          // compute half0
            union { int u[4]; short8 s; } uu;
            uu.u[0] = __builtin_amdgcn_ds_bpermute(bpidx, (int)pk2bf(pa[2*kb].x,   pa[2*kb].y));
            uu.u[1] = __builtin_amdgcn_ds_bpermute(bpidx, (int)pk2bf(pa[2*kb].z,   pa[2*kb].w));
            uu.u[2] = __builtin_amdgcn_ds_bpermute(bpidx, (int)pk2bf(pa[2*kb+1].x, pa[2*kb+1].y));
            uu.u[3] = __builtin_amdgcn_ds_bpermute(bpidx, (int)pk2bf(pa[2*kb+1].z, pa[2*kb+1].w));
            const short8* wp = (const short8*)&wfrag[(size_t)((kb * 4) * 64 + lane) * 8];
            a0 = __builtin_amdgcn_mfma_f32_16x16x32_bf16(uu.s, wp[0 * 64], a0, 0, 0, 0);
            a1 = __builtin_amdgcn_mfma_f32_16x16x32_bf16(uu.s, wp[1 * 64], a1, 0, 0, 0);
            a2 = __builtin_amdgcn_mfma_f32_16x16x32_bf16(uu.s, wp[2 * 64], a2, 0, 0, 0);
            a3 = __builtin_amdgcn_mfma_f32_16x16x32_bf16(uu.s, wp[3 * 64], a3, 0, 0, 0);
        }

        const int tn = t + G1_WSTRIDE;            // next tile's half0 in flight
        if (tn < NT16) {
            const float* xn = X + (size_t)tn * 16 * 256 + xoff;
            #pragma unroll
            for (int kb = 0; kb < 4; ++kb) {
                pa[2 * kb]     = __builtin_nontemporal_load((const f4raw*)(xn + kb * 32));
                pa[2 * kb + 1] = __builtin_nontemporal_load((const f4raw*)(xn + kb * 32 + 4));
            }
        }

        #pragma unroll
        for (int kb = 4; kb < 8; ++kb) {          // compute half1
            const int i = kb - 4;
            union { int u[4]; short8 s; } uu;
            uu.u[0] = __builtin_amdgcn_ds_bpermute(bpidx, (int)pk2bf(pb[2*i].x,   pb[2*i].y));
            uu.u[1] = __builtin_amdgcn_ds_bpermute(bpidx, (int)pk2bf(pb[2*i].z,   pb[2*i].w));
            uu.u[2] = __builtin_amdgcn_ds_bpermute(bpidx, (int)pk2bf(pb[2*i+1].x, pb[2*i+1].y));
            uu.u[3] = __builtin_amdgcn_ds_bpermute(bpidx, (int)pk2bf(pb[2*i+1].z, pb[2*i+1].w));
            const short8* wp = (const short8*)&wfrag[(size_t)((kb * 4) * 64 + lane) * 8];
            a0 = __builtin_amdgcn_mfma_f32_16x16x32_bf16(uu.s, wp[0 * 64], a0, 0, 0, 0);
            a1 = __builtin_amdgcn_mfma_f32_16x16x32_bf16(uu.s, wp[1 * 64], a1, 0, 0, 0);
            a2 = __builtin_amdgcn_mfma_f32_16x16x32_bf16(uu.s, wp[2 * 64], a2, 0, 0, 0);
            a3 = __builtin_amdgcn_mfma_f32_16x16x32_bf16(uu.s, wp[3 * 64], a3, 0, 0, 0);
        }

        // epilogue: direct store. D[q*4+r][ct*16+l16] = a_ct[r]; per (r,ct)
        // the 16 lanes of a q-group write 32 B contiguous — L2 merges lines.
        {
            unsigned short* hrow = h + (size_t)(t * 16) * 64;
            #pragma unroll
            for (int r = 0; r < 4; ++r) {
                const int row = q * 4 + r;
                hrow[row * 64 +  0 + l16] = f2bf(a0[r]);
                hrow[row * 64 + 16 + l16] = f2bf(a1[r]);
                hrow[row * 64 + 32 + l16] = f2bf(a2[r]);
                hrow[row * 64 + 48 + l16] = f2bf(a3[r]);
            }
        }
        t = tn;
    }
}

// ---------------------------------------------------------------------------
// Row gather, 8 lanes/row x uint4; colind/vals loads NON-TEMPORAL (stream-once)
// so they don't evict gather lines from L2.
// ---------------------------------------------------------------------------
__device__ inline void gather_row8(const unsigned short* __restrict__ B,
                                   const int* __restrict__ ci,
                                   const float* __restrict__ vv,
                                   int j8, float* __restrict__ acc)
{
    #pragma unroll
    for (int b = 0; b < 2; ++b) {
        i4raw c0 = __builtin_nontemporal_load((const i4raw*)ci + 2 * b);
        i4raw c1 = __builtin_nontemporal_load((const i4raw*)ci + 2 * b + 1);
        f4raw v0 = __builtin_nontemporal_load((const f4raw*)vv + 2 * b);
        f4raw v1 = __builtin_nontemporal_load((const f4raw*)vv + 2 * b + 1);
        uint4 g0 = *(const uint4*)(B + (size_t)c0.x * 64 + j8 * 8);
        uint4 g1 = *(const uint4*)(B + (size_t)c0.y * 64 + j8 * 8);
        uint4 g2 = *(const uint4*)(B + (size_t)c0.z * 64 + j8 * 8);
        uint4 g3 = *(const uint4*)(B + (size_t)c0.w * 64 + j8 * 8);
        uint4 g4 = *(const uint4*)(B + (size_t)c1.x * 64 + j8 * 8);
        uint4 g5 = *(const uint4*)(B + (size_t)c1.y * 64 + j8 * 8);
        uint4 g6 = *(const uint4*)(B + (size_t)c1.z * 64 + j8 * 8);
        uint4 g7 = *(const uint4*)(B + (size_t)c1.w * 64 + j8 * 8);
#define ACC8(g, s) \
        acc[0] += (s) * bflo((g).x); acc[1] += (s) * bfhi((g).x); \
        acc[2] += (s) * bflo((g).y); acc[3] += (s) * bfhi((g).y); \
        acc[4] += (s) * bflo((g).z); acc[5] += (s) * bfhi((g).z); \
        acc[6] += (s) * bflo((g).w); acc[7] += (s) * bfhi((g).w);
        ACC8(g0, v0.x) ACC8(g1, v0.y) ACC8(g2, v0.z) ACC8(g3, v0.w)
        ACC8(g4, v1.x) ACC8(g5, v1.y) ACC8(g6, v1.z) ACC8(g7, v1.w)
#undef ACC8
    }
}

// ---------------------------------------------------------------------------
// Fused SpMM1 + ReLU + GEMM2: o1 = bf16( relu(A @ h) @ W2 ).
// R6 RESTRUCTURE: 32 rows/block (grid 3125 exact), ONE 8-row gather batch
// per wave (was 16 rows = two serialized batches -> two miss-latency rounds
// per wave). All 4 waves stage into a shared 32-row LDS tile; MFMA work is
// split wave=(tile t=wid>>1, col-half ch=wid&1): 4 MFMA each; cooperative
// 256-thread epilogue store. LDS 12.8 KB, VGPR ~64 -> 8 blocks/CU.
// ---------------------------------------------------------------------------
__global__ __launch_bounds__(256) void spmm_gemm2(const int* __restrict__ colind,
                                                  const float* __restrict__ vals,
                                                  const unsigned short* __restrict__ h,
                                                  const float* __restrict__ W2,
                                                  unsigned short* __restrict__ o1)
{
    __shared__ unsigned short wfrag2[64 * 64];      // 8 KB
    __shared__ unsigned short stage[32 * 72];       // 4.5 KB, shared 32-row tile

    const int tid  = threadIdx.x;
    const int lane = tid & 63;
    const int wid  = tid >> 6;
    const int q    = lane >> 4;
    const int l16  = lane & 15;
    const int rl   = lane >> 3;
    const int j8   = lane & 7;

    // ---- W2 staging ----
    {
        const int r4 = tid >> 2;
        const int qt = tid & 3;
        float4 wr[4];
        #pragma unroll
        for (int i = 0; i < 4; ++i)
            wr[i] = *(const float4*)(W2 + r4 * 64 + qt * 16 + i * 4);
        const int kb  = r4 >> 5;
        const int j   = r4 & 7;
        const int lnr = ((r4 >> 3) & 3) * 16;
        #pragma unroll
        for (int c = 0; c < 16; ++c) {
            float f = ((c & 3) == 0) ? wr[c >> 2].x :
                      ((c & 3) == 1) ? wr[c >> 2].y :
                      ((c & 3) == 2) ? wr[c >> 2].z : wr[c >> 2].w;
            wfrag2[(((kb * 4) + qt) * 64 + lnr + c) * 8 + j] = f2bf(f);
        }
    }

    const int base = blockIdx.x * 32;               // 3125*32 = 100000 exact

    // ---- gather: one 8-deep batch per wave (8 rows, 8 lanes/row) ----
    const int lr  = wid * 8 + rl;                   // 0..31, block-local row
    const int row = base + lr;
    float acc[8] = {0.f,0.f,0.f,0.f,0.f,0.f,0.f,0.f};
    gather_row8(h, colind + (size_t)row * DEG, vals + (size_t)row * DEG, j8, acc);
    {
        uint4 pk;
        pk.x = pk2bf(fmaxf(acc[0], 0.f), fmaxf(acc[1], 0.f));
        pk.y = pk2bf(fmaxf(acc[2], 0.f), fmaxf(acc[3], 0.f));
        pk.z = pk2bf(fmaxf(acc[4], 0.f), fmaxf(acc[5], 0.f));
        pk.w = pk2bf(fmaxf(acc[6], 0.f), fmaxf(acc[7], 0.f));
        *(uint4*)&stage[lr * 72 + j8 * 8] = pk;
    }
    __syncthreads();            // all 32 staged rows visible (and wfrag2 done)

    // ---- GEMM2: wave (t, ch) does rows t*16..+16, cols ch*32..+32 ----
    const int t  = wid >> 1;
    const int ch = wid & 1;

    short8 af0 = *(const short8*)&stage[(t * 16 + l16) * 72 + 0 * 32 + q * 8];
    short8 af1 = *(const short8*)&stage[(t * 16 + l16) * 72 + 1 * 32 + q * 8];
    __syncthreads();            // A-frags in regs before stage is overwritten

    f32x4 b0 = {0,0,0,0}, b1 = {0,0,0,0};
    {
        const short8* wp0 = (const short8*)&wfrag2[(size_t)((0 * 4) * 64 + lane) * 8];
        const short8* wp1 = (const short8*)&wfrag2[(size_t)((1 * 4) * 64 + lane) * 8];
        const int c0 = 2 * ch, c1 = 2 * ch + 1;
        b0 = __builtin_amdgcn_mfma_f32_16x16x32_bf16(af0, wp0[c0 * 64], b0, 0, 0, 0);
        b0 = __builtin_amdgcn_mfma_f32_16x16x32_bf16(af1, wp1[c0 * 64], b0, 0, 0, 0);
        b1 = __builtin_amdgcn_mfma_f32_16x16x32_bf16(af0, wp0[c1 * 64], b1, 0, 0, 0);
        b1 = __builtin_amdgcn_mfma_f32_16x16x32_bf16(af1, wp1[c1 * 64], b1, 0, 0, 0);
    }

    // D[q*4+r][col]: col = (2ch + {0,1})*16 + l16 within the 16-row tile
    #pragma unroll
    for (int r = 0; r < 4; ++r) {
        const int srow = t * 16 + q * 4 + r;
        stage[srow * 72 + (2 * ch)     * 16 + l16] = f2bf(b0[r]);
        stage[srow * 72 + (2 * ch + 1) * 16 + l16] = f2bf(b1[r]);
    }
    __syncthreads();

    // ---- cooperative store: thread tid -> row tid>>3, 16B chunk tid&7 ----
    {
        const int srow = tid >> 3;
        const int c    = tid & 7;
        uint4 v = *(const uint4*)&stage[srow * 72 + c * 8];
        *(uint4*)(o1 + (size_t)(base + srow) * 64 + c * 8) = v;   // cached: spmm2 reuses
    }
}

// ---------------------------------------------------------------------------
// SpMM2: out(fp32) = A @ o1(bf16). Grid 3125 exact, no LDS.
// Cached float4 stores (R3): full-line merge in L2, WRITE_SIZE ~26 MB.
// ---------------------------------------------------------------------------
__global__ __launch_bounds__(256) void spmm_out(const int* __restrict__ colind,
                                                const float* __restrict__ vals,
                                                const unsigned short* __restrict__ B,
                                                float* __restrict__ out)
{
    const int tid  = threadIdx.x;
    const int lane = tid & 63;
    const int wid  = tid >> 6;
    const int rl   = lane >> 3;
    const int j8   = lane & 7;
    const int row  = blockIdx.x * 32 + wid * 8 + rl;   // 3125*32 = 100000 exact

    float acc[8] = {0.f,0.f,0.f,0.f,0.f,0.f,0.f,0.f};
    gather_row8(B, colind + (size_t)row * DEG, vals + (size_t)row * DEG, j8, acc);

    f4raw lo = { acc[0], acc[1], acc[2], acc[3] };
    f4raw hi = { acc[4], acc[5], acc[6], acc[7] };
    float* op = out + (size_t)row * 64 + j8 * 8;
    *(f4raw*)op       = lo;     // cached: full-line merge in L2
    *(f4raw*)(op + 4) = hi;
}

extern "C" void kernel_launch(void* const* d_in, const int* in_sizes, int n_in,
                              void* d_out, int out_size, void* d_ws, size_t ws_size,
                              hipStream_t stream) {
    const float* X      = (const float*)d_in[0];   // [N,256]
    const float* W1     = (const float*)d_in[1];   // [256,64]
    const float* W2     = (const float*)d_in[2];   // [64,64]
    const float* vals   = (const float*)d_in[3];   // [NNZ]
    // d_in[4] = rowptr (fixed degree, unused)
    const int*   colind = (const int*)d_in[5];     // [NNZ]
    float*       out    = (float*)d_out;           // [N,64] fp32

    unsigned short* h  = (unsigned short*)d_ws;        // [N,64] bf16
    unsigned short* o1 = h + (size_t)N_NODES * 64;     // [N,64] bf16 (no alias)

    hipLaunchKernelGGL(gemm1_k256, dim3(G1_BLOCKS), dim3(256), 0, stream, X, W1, h);
    hipLaunchKernelGGL(spmm_gemm2, dim3(NB32), dim3(256), 0, stream,
                       colind, vals, h, W2, o1);
    hipLaunchKernelGGL(spmm_out, dim3(NB32), dim3(256), 0, stream,
                       colind, vals, o1, out);
}